// Round 3
// baseline (1793.060 us; speedup 1.0000x reference)
//
#include <hip/hip_runtime.h>
#include <hip/hip_bf16.h>

// Decoder: 6 layers of {SA, LN2d, CA, LN2d, FFN, LN2d}.
// L=6 H=8 C=512 DH=64 FF=2048 B=64 T=S=128.
// I/O is FLOAT32 (per reference dtypes); internal GEMM/attn compute in bf16
// (harness grants bf16-floor threshold). Residual stream kept fp32.

typedef __bf16 bf16;
typedef bf16 bf16x8 __attribute__((ext_vector_type(8)));
typedef bf16 bf16x4 __attribute__((ext_vector_type(4)));
typedef float f32x4 __attribute__((ext_vector_type(4)));

#define MFMA16(a, b, c) __builtin_amdgcn_mfma_f32_16x16x32_bf16(a, b, c, 0, 0, 0)

static constexpr int L_ = 6, H_ = 8, C_ = 512, DH_ = 64, FF_ = 2048;
static constexpr int B_ = 64, T_ = 128, S_ = 128;
static constexpr int M_ = B_ * T_;  // 8192 rows of the activation stream

// ---------------------------------------------------------------------------
// 64x64 tile transpose + fp32->bf16 convert for weight repacking.
// src: matrices [R][C] fp32 row-major; matrix m (=blockIdx.z) goes to
//   dst + m*dhs + dbase  as [C][R] bf16 row-major.
__global__ __launch_bounds__(256) void transpose_f32_bf16(
    const float* __restrict__ src, bf16* __restrict__ dst,
    int R, int C, int dhs, int dbase)
{
    __shared__ alignas(16) float t[64][68];
    const int m = blockIdx.z;
    const int r0 = blockIdx.y * 64, c0 = blockIdx.x * 64;
    const float* s = src + (size_t)m * R * C;
    bf16* d = dst + (size_t)m * dhs + dbase;
    const int tr = threadIdx.x >> 4;        // 0..15
    const int tc = (threadIdx.x & 15) * 4;  // 0..60
#pragma unroll
    for (int ro = 0; ro < 64; ro += 16)
        *(float4*)&t[tr + ro][tc] = *(const float4*)(s + (size_t)(r0 + tr + ro) * C + c0 + tc);
    __syncthreads();
    const int wc = (threadIdx.x & 7) * 8;
#pragma unroll
    for (int po = 0; po < 2; ++po) {
        const int oc = (threadIdx.x >> 3) + po * 32;  // original column
        bf16x8 v;
#pragma unroll
        for (int j = 0; j < 8; ++j) v[j] = (bf16)t[wc + j][oc];
        *(bf16x8*)(d + (size_t)(c0 + oc) * R + r0 + wc) = v;
    }
}

// ---------------------------------------------------------------------------
// fp32 -> bf16 convert, 8 elems/thread
__global__ __launch_bounds__(256) void to_bf16(
    const float* __restrict__ in, bf16* __restrict__ out)
{
    const size_t i = ((size_t)blockIdx.x * 256 + threadIdx.x) * 8;
    float4 f0 = *(const float4*)(in + i);
    float4 f1 = *(const float4*)(in + i + 4);
    bf16x8 v = {(bf16)f0.x, (bf16)f0.y, (bf16)f0.z, (bf16)f0.w,
                (bf16)f1.x, (bf16)f1.y, (bf16)f1.z, (bf16)f1.w};
    *(bf16x8*)(out + i) = v;
}

// ---------------------------------------------------------------------------
// GEMM: out[M][N] = A[M][K] * BT[N][K]^T (+bias, epilogue per MODE), M=8192.
// 128x128 tile, BK=32, 4 waves each computing 64x64 via 4x4 mfma_16x16x32_bf16.
// MODE 0: SA QKV (N=1536): n -> p(q/k/v),h,d ; q/k:[BH][T][64], v:[BH][64][S]
// MODE 1: CA Q   (N=512)
// MODE 2: CA KV  (N=1024): p=0->k, p=1->vT (A rows are encoder b,s)
// MODE 3: FFN1   (bias+relu, bf16 row-major out [M][2048])
// MODE 4: FFN2   (bias, fp32 row-major out [M][512])
template <int MODE>
__global__ __launch_bounds__(256) void gemm_bt(
    const bf16* __restrict__ A, const bf16* __restrict__ BT,
    const float* __restrict__ b0, const float* __restrict__ b1, const float* __restrict__ b2,
    bf16* __restrict__ o0, bf16* __restrict__ o1, bf16* __restrict__ o2,
    float* __restrict__ o32, int N, int K)
{
    __shared__ alignas(16) bf16 as[128][40];
    __shared__ alignas(16) bf16 bs[128][40];
    const int tid = threadIdx.x;
    const int wave = tid >> 6, lane = tid & 63;
    const int m0 = blockIdx.y * 128, n0 = blockIdx.x * 128;
    const int lr = tid >> 1, lc = (tid & 1) * 16;
    const int wr = (wave >> 1) * 64, wc = (wave & 1) * 64;
    const int fr = lane & 15, fq = lane >> 4;

    f32x4 acc[4][4] = {};
    const bf16* pa = A + (size_t)(m0 + lr) * K + lc;
    const bf16* pb = BT + (size_t)(n0 + lr) * K + lc;

    for (int k0 = 0; k0 < K; k0 += 32) {
        uint4 a0 = *(const uint4*)(pa + k0);
        uint4 a1 = *(const uint4*)(pa + k0 + 8);
        uint4 b0v = *(const uint4*)(pb + k0);
        uint4 b1v = *(const uint4*)(pb + k0 + 8);
        __syncthreads();
        *(uint4*)&as[lr][lc] = a0;
        *(uint4*)&as[lr][lc + 8] = a1;
        *(uint4*)&bs[lr][lc] = b0v;
        *(uint4*)&bs[lr][lc + 8] = b1v;
        __syncthreads();
        bf16x8 af[4], bfv[4];
#pragma unroll
        for (int mi = 0; mi < 4; ++mi) af[mi] = *(const bf16x8*)&as[wr + mi * 16 + fr][fq * 8];
#pragma unroll
        for (int ni = 0; ni < 4; ++ni) bfv[ni] = *(const bf16x8*)&bs[wc + ni * 16 + fr][fq * 8];
#pragma unroll
        for (int mi = 0; mi < 4; ++mi)
#pragma unroll
            for (int ni = 0; ni < 4; ++ni)
                acc[mi][ni] = MFMA16(af[mi], bfv[ni], acc[mi][ni]);
    }

#pragma unroll
    for (int mi = 0; mi < 4; ++mi) {
#pragma unroll
        for (int ni = 0; ni < 4; ++ni) {
            const int n = n0 + wc + ni * 16 + fr;
#pragma unroll
            for (int reg = 0; reg < 4; ++reg) {
                const int r = m0 + wr + mi * 16 + fq * 4 + reg;
                float val = acc[mi][ni][reg];
                if constexpr (MODE == 0 || MODE == 2) {
                    const int p = n >> 9, hd = n & 511, d = n & 63, hh = (n >> 6) & 7;
                    const int bb = r >> 7, tt = r & 127;
                    const float* bias;
                    if constexpr (MODE == 0) bias = (p == 0) ? b0 : (p == 1 ? b1 : b2);
                    else bias = (p == 0) ? b1 : b2;
                    val += bias[hd];
                    const size_t bh = (size_t)(bb * 8 + hh);
                    if constexpr (MODE == 0) {
                        if (p == 0)      o0[(bh * 128 + tt) * 64 + d] = (bf16)val;
                        else if (p == 1) o1[(bh * 128 + tt) * 64 + d] = (bf16)val;
                        else             o2[(bh * 64 + d) * 128 + tt] = (bf16)val;
                    } else {
                        if (p == 0)      o1[(bh * 128 + tt) * 64 + d] = (bf16)val;
                        else             o2[(bh * 64 + d) * 128 + tt] = (bf16)val;
                    }
                } else if constexpr (MODE == 1) {
                    const int d = n & 63, hh = (n >> 6) & 7;
                    const int bb = r >> 7, tt = r & 127;
                    val += b0[n];
                    o0[((size_t)(bb * 8 + hh) * 128 + tt) * 64 + d] = (bf16)val;
                } else if constexpr (MODE == 3) {
                    val += b0[n];
                    val = fmaxf(val, 0.f);
                    o0[(size_t)r * 2048 + n] = (bf16)val;
                } else {  // MODE 4
                    val += b0[n];
                    o32[(size_t)r * 512 + n] = val;
                }
            }
        }
    }
}

// ---------------------------------------------------------------------------
// Attention for one (b,h): out[b,t,h*64+d] = softmax(Q K^T / 8) V, fp32 out.
// Q,K: [BH][128][64]; vT: [BH][64][128]. Scores staged bf16 in LDS.
__global__ __launch_bounds__(256) void attn_kernel(
    const bf16* __restrict__ q, const bf16* __restrict__ k,
    const bf16* __restrict__ vT, float* __restrict__ out)
{
    __shared__ alignas(16) bf16 sP[128][136];
    __shared__ float sInv[128];
    const int bh = blockIdx.x;
    const int bb = bh >> 3, hh = bh & 7;
    const bf16* Q = q + (size_t)bh * 128 * 64;
    const bf16* Kp = k + (size_t)bh * 128 * 64;
    const bf16* V = vT + (size_t)bh * 64 * 128;
    const int tid = threadIdx.x, wave = tid >> 6, lane = tid & 63;
    const int wr = (wave >> 1) * 64, wc = (wave & 1) * 64;
    const int fr = lane & 15, fq = lane >> 4;

    // S = Q K^T (M=N=128, K=64), fragments straight from global (L1/L2-hot)
    f32x4 acc[4][4] = {};
#pragma unroll
    for (int k0 = 0; k0 < 64; k0 += 32) {
        bf16x8 af[4], bfv[4];
#pragma unroll
        for (int mi = 0; mi < 4; ++mi)
            af[mi] = *(const bf16x8*)(Q + (size_t)(wr + mi * 16 + fr) * 64 + k0 + fq * 8);
#pragma unroll
        for (int ni = 0; ni < 4; ++ni)
            bfv[ni] = *(const bf16x8*)(Kp + (size_t)(wc + ni * 16 + fr) * 64 + k0 + fq * 8);
#pragma unroll
        for (int mi = 0; mi < 4; ++mi)
#pragma unroll
            for (int ni = 0; ni < 4; ++ni)
                acc[mi][ni] = MFMA16(af[mi], bfv[ni], acc[mi][ni]);
    }
#pragma unroll
    for (int mi = 0; mi < 4; ++mi)
#pragma unroll
        for (int ni = 0; ni < 4; ++ni)
#pragma unroll
            for (int reg = 0; reg < 4; ++reg) {
                const int r = wr + mi * 16 + fq * 4 + reg;
                const int c = wc + ni * 16 + fr;
                sP[r][c] = (bf16)(acc[mi][ni][reg] * 0.125f);
            }
    __syncthreads();

    // softmax rows: 2 threads per row (adjacent lanes -> shfl_xor(1) combine)
    {
        const int r = tid >> 1, h0 = (tid & 1) * 64;
        float mx = -3.0e38f;
        for (int j = 0; j < 64; ++j) mx = fmaxf(mx, (float)sP[r][h0 + j]);
        mx = fmaxf(mx, __shfl_xor(mx, 1));
        float sum = 0.f;
        for (int j = 0; j < 64; ++j) {
            float p = __expf((float)sP[r][h0 + j] - mx);
            sum += p;
            sP[r][h0 + j] = (bf16)p;  // unnormalized P; 1/sum folded into epilogue
        }
        sum += __shfl_xor(sum, 1);
        if ((tid & 1) == 0) sInv[r] = 1.f / sum;
    }
    __syncthreads();

    // O = P V (M=128, N=64, K=128); each wave does 32 rows x 64 cols
    f32x4 acc2[2][4] = {};
#pragma unroll
    for (int k0 = 0; k0 < 128; k0 += 32) {
        bf16x8 af[2], bfv[4];
#pragma unroll
        for (int mi = 0; mi < 2; ++mi)
            af[mi] = *(const bf16x8*)&sP[wave * 32 + mi * 16 + fr][k0 + fq * 8];
#pragma unroll
        for (int ni = 0; ni < 4; ++ni)
            bfv[ni] = *(const bf16x8*)(V + (size_t)(ni * 16 + fr) * 128 + k0 + fq * 8);
#pragma unroll
        for (int mi = 0; mi < 2; ++mi)
#pragma unroll
            for (int ni = 0; ni < 4; ++ni)
                acc2[mi][ni] = MFMA16(af[mi], bfv[ni], acc2[mi][ni]);
    }
#pragma unroll
    for (int mi = 0; mi < 2; ++mi)
#pragma unroll
        for (int ni = 0; ni < 4; ++ni)
#pragma unroll
            for (int reg = 0; reg < 4; ++reg) {
                const int r = wave * 32 + mi * 16 + fq * 4 + reg;
                const int d = ni * 16 + fr;
                out[((size_t)(bb * 128 + r)) * 512 + hh * 64 + d] = acc2[mi][ni][reg] * sInv[r];
            }
}

// ---------------------------------------------------------------------------
// LayerNorm over (T,C)=65536 per batch on y = x32 + sub32.
// stats: 4 blocks per batch write partial (sum, sumsq).
__global__ __launch_bounds__(256) void ln_stats(
    const float* __restrict__ x, const float* __restrict__ sub, float2* __restrict__ part)
{
    const int bid = blockIdx.x;
    const size_t base = (size_t)(bid >> 2) * 65536 + (size_t)(bid & 3) * 16384;
    float s = 0.f, ss = 0.f;
#pragma unroll
    for (int j = 0; j < 16; ++j) {
        const size_t off = base + (size_t)(j * 256 + threadIdx.x) * 4;
        float4 xv = *(const float4*)(x + off);
        float4 sv = *(const float4*)(sub + off);
        float y0 = xv.x + sv.x, y1 = xv.y + sv.y, y2 = xv.z + sv.z, y3 = xv.w + sv.w;
        s += y0 + y1 + y2 + y3;
        ss += y0 * y0 + y1 * y1 + y2 * y2 + y3 * y3;
    }
    for (int off = 32; off; off >>= 1) { s += __shfl_xor(s, off); ss += __shfl_xor(ss, off); }
    __shared__ float sa[4], sb[4];
    const int wave = threadIdx.x >> 6, lane = threadIdx.x & 63;
    if (lane == 0) { sa[wave] = s; sb[wave] = ss; }
    __syncthreads();
    if (threadIdx.x == 0)
        part[bid] = make_float2(sa[0] + sa[1] + sa[2] + sa[3], sb[0] + sb[1] + sb[2] + sb[3]);
}

// apply: normalize, update fp32 stream in place, emit bf16 copy (+ optional fp32 out).
__global__ __launch_bounds__(256) void ln_apply(
    float* __restrict__ x, const float* __restrict__ sub,
    const float2* __restrict__ part, bf16* __restrict__ xout,
    float* __restrict__ out32)
{
    const int bid = blockIdx.x;
    float S = 0.f, SS = 0.f;
#pragma unroll
    for (int i = 0; i < 4; ++i) { float2 p = part[(bid & ~3) + i]; S += p.x; SS += p.y; }
    const float inv = 1.f / 65536.f;
    const float mu = S * inv;
    const float var = SS * inv - mu * mu;
    const float rstd = rsqrtf(var + 1e-5f);
    const size_t base = (size_t)(bid >> 2) * 65536 + (size_t)(bid & 3) * 16384;
#pragma unroll
    for (int j = 0; j < 16; ++j) {
        const size_t off = base + (size_t)(j * 256 + threadIdx.x) * 4;
        float4 xv = *(const float4*)(x + off);
        float4 sv = *(const float4*)(sub + off);
        float o0 = (xv.x + sv.x - mu) * rstd;
        float o1 = (xv.y + sv.y - mu) * rstd;
        float o2 = (xv.z + sv.z - mu) * rstd;
        float o3 = (xv.w + sv.w - mu) * rstd;
        float4 ov = {o0, o1, o2, o3};
        *(float4*)(x + off) = ov;
        bf16x4 bv = {(bf16)o0, (bf16)o1, (bf16)o2, (bf16)o3};
        *(bf16x4*)(xout + off) = bv;
        if (out32) *(float4*)(out32 + off) = ov;
    }
}

// ---------------------------------------------------------------------------
extern "C" void kernel_launch(void* const* d_in, const int* in_sizes, int n_in,
                              void* d_out, int out_size, void* d_ws, size_t ws_size,
                              hipStream_t stream)
{
    (void)in_sizes; (void)n_in; (void)out_size; (void)ws_size;
    const float* x_in  = (const float*)d_in[0];
    const float* enc   = (const float*)d_in[1];
    const float* sa_wq = (const float*)d_in[2];
    const float* sa_bq = (const float*)d_in[3];
    const float* sa_wk = (const float*)d_in[4];
    const float* sa_bk = (const float*)d_in[5];
    const float* sa_wv = (const float*)d_in[6];
    const float* sa_bv = (const float*)d_in[7];
    const float* ca_wq = (const float*)d_in[8];
    const float* ca_bq = (const float*)d_in[9];
    const float* ca_wk = (const float*)d_in[10];
    const float* ca_bk = (const float*)d_in[11];
    const float* ca_wv = (const float*)d_in[12];
    const float* ca_bv = (const float*)d_in[13];
    const float* ff_w1 = (const float*)d_in[14];
    const float* ff_b1 = (const float*)d_in[15];
    const float* ff_w2 = (const float*)d_in[16];
    const float* ff_b2 = (const float*)d_in[17];

    char* wsp = (char*)d_ws;
    auto alloc = [&](size_t bytes) -> char* {
        char* p = wsp;
        wsp += (bytes + 255) & ~(size_t)255;
        return p;
    };
    // ws layout (~88 MB total):
    float* x32   = (float*)alloc((size_t)M_ * 512 * 4);         // fp32 residual stream (16M)
    float* sub32 = (float*)alloc((size_t)M_ * 512 * 4);         // sublayer output (16M)
    bf16*  xbf   = (bf16*)alloc((size_t)M_ * 512 * 2);          // bf16 GEMM operand (8M)
    bf16*  encbf = (bf16*)alloc((size_t)M_ * 512 * 2);          // bf16 encoder copy (8M)
    char*  shreg = alloc((size_t)M_ * 2048 * 2);                // attn bufs / FFN hidden (32M)
    bf16*  Wsa   = (bf16*)alloc((size_t)1536 * 512 * 2);        // per-layer repacked weights
    bf16*  Wcaq  = (bf16*)alloc((size_t)512 * 512 * 2);
    bf16*  Wcakv = (bf16*)alloc((size_t)1024 * 512 * 2);
    bf16*  Wff1  = (bf16*)alloc((size_t)2048 * 512 * 2);
    bf16*  Wff2  = (bf16*)alloc((size_t)512 * 2048 * 2);
    float2* part = (float2*)alloc(256 * sizeof(float2));

    // aliased views of the shared region
    bf16* qb   = (bf16*)shreg;                                    // [BH][T][64]   (8M)
    bf16* kb   = (bf16*)(shreg + (size_t)512 * 128 * 64 * 2);     // [BH][T][64]   (8M)
    bf16* vTb  = (bf16*)(shreg + (size_t)2 * 512 * 128 * 64 * 2); // [BH][64][S]   (8M)
    bf16* hbuf = (bf16*)shreg;                                    // [M][2048]     (32M)

    dim3 tb(256);
    hipMemcpyAsync(x32, x_in, (size_t)M_ * 512 * 4, hipMemcpyDeviceToDevice, stream);
    to_bf16<<<2048, tb, 0, stream>>>(x_in, xbf);
    to_bf16<<<2048, tb, 0, stream>>>(enc, encbf);

    for (int l = 0; l < L_; ++l) {
        const size_t wo = (size_t)l * 8 * 512 * 64;   // per-layer weight offset (per-head mats)
        // ---- per-layer weight repack ([C][DH]->[DH][C] per head; FF transposes)
        transpose_f32_bf16<<<dim3(1, 8, 8), tb, 0, stream>>>(sa_wq + wo, Wsa,   512, 64, 64 * 512, 0);
        transpose_f32_bf16<<<dim3(1, 8, 8), tb, 0, stream>>>(sa_wk + wo, Wsa,   512, 64, 64 * 512, 512 * 512);
        transpose_f32_bf16<<<dim3(1, 8, 8), tb, 0, stream>>>(sa_wv + wo, Wsa,   512, 64, 64 * 512, 1024 * 512);
        transpose_f32_bf16<<<dim3(1, 8, 8), tb, 0, stream>>>(ca_wq + wo, Wcaq,  512, 64, 64 * 512, 0);
        transpose_f32_bf16<<<dim3(1, 8, 8), tb, 0, stream>>>(ca_wk + wo, Wcakv, 512, 64, 64 * 512, 0);
        transpose_f32_bf16<<<dim3(1, 8, 8), tb, 0, stream>>>(ca_wv + wo, Wcakv, 512, 64, 64 * 512, 512 * 512);
        transpose_f32_bf16<<<dim3(32, 8, 1), tb, 0, stream>>>(ff_w1 + (size_t)l * 512 * 2048, Wff1, 512, 2048, 0, 0);
        transpose_f32_bf16<<<dim3(8, 32, 1), tb, 0, stream>>>(ff_w2 + (size_t)l * 2048 * 512, Wff2, 2048, 512, 0, 0);

        // ---- self attention
        gemm_bt<0><<<dim3(12, 64), tb, 0, stream>>>(xbf, Wsa,
            sa_bq + l * 512, sa_bk + l * 512, sa_bv + l * 512,
            qb, kb, vTb, nullptr, 1536, 512);
        attn_kernel<<<512, tb, 0, stream>>>(qb, kb, vTb, sub32);
        ln_stats<<<256, tb, 0, stream>>>(x32, sub32, part);
        ln_apply<<<256, tb, 0, stream>>>(x32, sub32, part, xbf, nullptr);
        // ---- cross attention
        gemm_bt<1><<<dim3(4, 64), tb, 0, stream>>>(xbf, Wcaq,
            ca_bq + l * 512, nullptr, nullptr,
            qb, nullptr, nullptr, nullptr, 512, 512);
        gemm_bt<2><<<dim3(8, 64), tb, 0, stream>>>(encbf, Wcakv,
            nullptr, ca_bk + l * 512, ca_bv + l * 512,
            nullptr, kb, vTb, nullptr, 1024, 512);
        attn_kernel<<<512, tb, 0, stream>>>(qb, kb, vTb, sub32);
        ln_stats<<<256, tb, 0, stream>>>(x32, sub32, part);
        ln_apply<<<256, tb, 0, stream>>>(x32, sub32, part, xbf, nullptr);
        // ---- feed-forward
        gemm_bt<3><<<dim3(16, 64), tb, 0, stream>>>(xbf, Wff1,
            ff_b1 + l * 2048, nullptr, nullptr,
            hbuf, nullptr, nullptr, nullptr, 2048, 512);
        gemm_bt<4><<<dim3(4, 64), tb, 0, stream>>>(hbuf, Wff2,
            ff_b2 + l * 512, nullptr, nullptr,
            nullptr, nullptr, nullptr, sub32, 512, 2048);
        ln_stats<<<256, tb, 0, stream>>>(x32, sub32, part);
        ln_apply<<<256, tb, 0, stream>>>(x32, sub32, part, xbf,
            (l == L_ - 1) ? (float*)d_out : nullptr);
    }
}

// Round 4
// 1523.792 us; speedup vs baseline: 1.1767x; 1.1767x over previous
//
#include <hip/hip_runtime.h>
#include <hip/hip_bf16.h>

// Decoder: 6 layers of {SA, LN2d, CA, LN2d, FFN, LN2d}. fp32 I/O, bf16 MFMA.
// R4: (a) global_load_lds(16B) staging, unpadded LDS tiles (m97 pattern);
//     (b) BM=64 tiles for small-N GEMMs (grid >= 512 everywhere);
//     (c) LN folded into GEMM epilogues via linearity:
//         LN(y)W + b = rstd*(yW) + (b - mu*rstd*colsum(W)).
//         Stream = unnormalized y (fp32) + per-batch (sum,sumsq) via fused
//         atomics in producer epilogues. No standalone LN kernels.

typedef __bf16 bf16;
typedef bf16 bf16x8 __attribute__((ext_vector_type(8)));
typedef float f32x4 __attribute__((ext_vector_type(4)));

#define MFMA16(a, b, c) __builtin_amdgcn_mfma_f32_16x16x32_bf16(a, b, c, 0, 0, 0)

// async global->LDS, 16B/lane; LDS dest = wave-uniform base + lane*16
#define GLL16(gsrc, ldst)                                                          \
    __builtin_amdgcn_global_load_lds(                                              \
        (const __attribute__((address_space(1))) void*)(gsrc),                     \
        (__attribute__((address_space(3))) void*)(ldst), 16, 0, 0)

static constexpr int L_ = 6, C_ = 512, FF_ = 2048;
static constexpr int B_ = 64, T_ = 128;
static constexpr int M_ = B_ * T_;       // 8192
static constexpr float LNINV = 1.f / 65536.f;
static constexpr float EPS_ = 1e-5f;

// ---------------------------------------------------------------------------
__global__ __launch_bounds__(256) void zero_part(float* __restrict__ p) {
    for (int i = threadIdx.x; i < 18 * 64 * 2; i += 256) p[i] = 0.f;
}

// x (fp32) -> y stream copy + bf16 operand
__global__ __launch_bounds__(256) void init_x(
    const float* __restrict__ xin, float* __restrict__ y, bf16* __restrict__ yb)
{
    const size_t i = ((size_t)blockIdx.x * 256 + threadIdx.x) * 8;
    float4 f0 = *(const float4*)(xin + i);
    float4 f1 = *(const float4*)(xin + i + 4);
    *(float4*)(y + i) = f0;
    *(float4*)(y + i + 4) = f1;
    bf16x8 v = {(bf16)f0.x, (bf16)f0.y, (bf16)f0.z, (bf16)f0.w,
                (bf16)f1.x, (bf16)f1.y, (bf16)f1.z, (bf16)f1.w};
    *(bf16x8*)(yb + i) = v;
}

__global__ __launch_bounds__(256) void to_bf16(
    const float* __restrict__ in, bf16* __restrict__ out)
{
    const size_t i = ((size_t)blockIdx.x * 256 + threadIdx.x) * 8;
    float4 f0 = *(const float4*)(in + i);
    float4 f1 = *(const float4*)(in + i + 4);
    bf16x8 v = {(bf16)f0.x, (bf16)f0.y, (bf16)f0.z, (bf16)f0.w,
                (bf16)f1.x, (bf16)f1.y, (bf16)f1.z, (bf16)f1.w};
    *(bf16x8*)(out + i) = v;
}

// ---------------------------------------------------------------------------
// Generic 64x64-tile fp32->bf16 transpose: src [R][C] -> dst [C][R]. grid z=1.
__global__ __launch_bounds__(256) void transpose_f32_bf16(
    const float* __restrict__ src, bf16* __restrict__ dst, int R, int C)
{
    __shared__ alignas(16) float t[64][68];
    const int r0 = blockIdx.y * 64, c0 = blockIdx.x * 64;
    const int tr = threadIdx.x >> 4;
    const int tc = (threadIdx.x & 15) * 4;
#pragma unroll
    for (int ro = 0; ro < 64; ro += 16)
        *(float4*)&t[tr + ro][tc] = *(const float4*)(src + (size_t)(r0 + tr + ro) * C + c0 + tc);
    __syncthreads();
    const int wc = (threadIdx.x & 7) * 8;
#pragma unroll
    for (int po = 0; po < 2; ++po) {
        const int oc = (threadIdx.x >> 3) + po * 32;
        bf16x8 v;
#pragma unroll
        for (int j = 0; j < 8; ++j) v[j] = (bf16)t[wc + j][oc];
        *(bf16x8*)(dst + (size_t)(c0 + oc) * R + r0 + wc) = v;
    }
}

// All per-head projection mats for all layers in one launch. z in [0,288):
// type=z/48 in {sa_wq,sa_wk,sa_wv,ca_wq,ca_wk,ca_wv}, l=(z%48)/8, h=z%8.
// Each mat [512][64] fp32 -> [64][512] bf16 at the GEMM's BT row index.
__global__ __launch_bounds__(256) void head_repack(
    const float* __restrict__ sa_wq, const float* __restrict__ sa_wk,
    const float* __restrict__ sa_wv, const float* __restrict__ ca_wq,
    const float* __restrict__ ca_wk, const float* __restrict__ ca_wv,
    bf16* __restrict__ Wsa, bf16* __restrict__ Wcaq, bf16* __restrict__ Wcakv)
{
    __shared__ alignas(16) float t[64][68];
    const int z = blockIdx.z;
    const int type = z / 48, rem = z % 48, l = rem >> 3, h = rem & 7;
    const float* srcs[6] = {sa_wq, sa_wk, sa_wv, ca_wq, ca_wk, ca_wv};
    const float* s = srcs[type] + (size_t)(l * 8 + h) * 512 * 64;
    bf16* d;
    if (type < 3)       d = Wsa   + ((size_t)l * 1536 + type * 512 + h * 64) * 512;
    else if (type == 3) d = Wcaq  + ((size_t)l * 512 + h * 64) * 512;
    else                d = Wcakv + ((size_t)l * 1024 + (type - 4) * 512 + h * 64) * 512;
    const int r0 = blockIdx.y * 64;  // over R=512; C=64 single tile
    const int tr = threadIdx.x >> 4;
    const int tc = (threadIdx.x & 15) * 4;
#pragma unroll
    for (int ro = 0; ro < 64; ro += 16)
        *(float4*)&t[tr + ro][tc] = *(const float4*)(s + (size_t)(r0 + tr + ro) * 64 + tc);
    __syncthreads();
    const int wc = (threadIdx.x & 7) * 8;
#pragma unroll
    for (int po = 0; po < 2; ++po) {
        const int oc = (threadIdx.x >> 3) + po * 32;  // original col (d)
        bf16x8 v;
#pragma unroll
        for (int j = 0; j < 8; ++j) v[j] = (bf16)t[wc + j][oc];
        *(bf16x8*)(d + (size_t)oc * 512 + r0 + wc) = v;
    }
}

// Column sums of the fixup-needing weights, from the ORIGINAL fp32 layouts.
// t in [0, 6*4096): l = t>>12; u<1536 -> Wsa order (p*512+h*64+d);
// u<2048 -> ca_wq (h*64+d); else ff_w1 (f).
__global__ __launch_bounds__(256) void colsum_all(
    const float* __restrict__ sa_wq, const float* __restrict__ sa_wk,
    const float* __restrict__ sa_wv, const float* __restrict__ ca_wq,
    const float* __restrict__ ff_w1,
    float* __restrict__ csA, float* __restrict__ csQ, float* __restrict__ csF)
{
    const int t = blockIdx.x * 256 + threadIdx.x;
    const int l = t >> 12, u = t & 4095;
    float sum = 0.f;
    if (u < 1536) {
        const int p = u >> 9, h = (u >> 6) & 7, d = u & 63;
        const float* w = (p == 0) ? sa_wq : (p == 1) ? sa_wk : sa_wv;
        const float* base = w + (size_t)(l * 8 + h) * 512 * 64 + d;
        for (int c = 0; c < 512; ++c) sum += base[(size_t)c * 64];
        csA[l * 1536 + u] = sum;
    } else if (u < 2048) {
        const int v = u - 1536, h = v >> 6, d = v & 63;
        const float* base = ca_wq + (size_t)(l * 8 + h) * 512 * 64 + d;
        for (int c = 0; c < 512; ++c) sum += base[(size_t)c * 64];
        csQ[l * 512 + v] = sum;
    } else {
        const int f = u - 2048;
        const float* base = ff_w1 + (size_t)l * 512 * 2048 + f;
        for (int c = 0; c < 512; ++c) sum += base[(size_t)c * 2048];
        csF[l * 2048 + f] = sum;
    }
}

// ---------------------------------------------------------------------------
// GEMM out[M][N] = A[M][K] * BT[N][K]^T, m97-style GLL staging, BK=32.
// BM in {128, 64}; BN=128. BM128: 4 waves 2x2 of 64x64 (4x4 mfma tiles);
// BM64: 4 waves side-by-side 64x32 (4x2 tiles).
// LN fixup (slotPrev>=0): val*rstd + bias - mu*rstd*cs[n].
// MODE 0: SA QKV (N=1536, fixup) -> qb/kb/vTb
// MODE 1: CA Q   (N=512, fixup)  -> qb
// MODE 2: CA KV  (N=1024, plain bias) -> kb/vTb
// MODE 3: FFN1   (fixup + relu) -> hbuf bf16
// MODE 4: FFN2   (plain bias + residual-normfix add into y, fused stats)
template <int MODE, int BM>
__global__ __launch_bounds__(256) void gemm_bt(
    const bf16* __restrict__ A, const bf16* __restrict__ BT,
    const float* __restrict__ b0, const float* __restrict__ b1,
    const float* __restrict__ b2, const float* __restrict__ cs,
    float2* __restrict__ part, int slotPrev, int slotNew,
    bf16* __restrict__ o0, bf16* __restrict__ o1, bf16* __restrict__ o2,
    float* __restrict__ y, bf16* __restrict__ ybf, int N, int K)
{
    constexpr int MI = 4;
    constexpr int NI = (BM == 128) ? 4 : 2;
    __shared__ alignas(16) bf16 as[BM][32];
    __shared__ alignas(16) bf16 bs[128][32];
    const int tid = threadIdx.x, wave = tid >> 6, lane = tid & 63;
    const int m0 = blockIdx.y * BM, n0 = blockIdx.x * 128;
    const int wr = (BM == 128) ? (wave >> 1) * 64 : 0;
    const int wc = (BM == 128) ? (wave & 1) * 64 : wave * 32;
    const int fr = lane & 15, fq = lane >> 4;
    const int srow = lane >> 2, schunk = (lane & 3) * 8;

    float mu = 0.f, rstd = 1.f;
    if (slotPrev >= 0) {
        float2 p = part[slotPrev * 64 + (m0 >> 7)];
        mu = p.x * LNINV;
        rstd = rsqrtf(p.y * LNINV - mu * mu + EPS_);
    }

    const bf16* pa = A + (size_t)(m0 + wave * 16 + srow) * K + schunk;
    const bf16* pb = BT + (size_t)(n0 + wave * 16 + srow) * K + schunk;
    bf16* lA = &as[wave * 16][0];
    bf16* lB = &bs[wave * 16][0];

    f32x4 acc[MI][NI] = {};
    for (int k0 = 0; k0 < K; k0 += 32) {
        __syncthreads();
        GLL16(pa + k0, lA);
        if constexpr (BM == 128) GLL16(pa + k0 + (size_t)64 * K, lA + 64 * 32);
        GLL16(pb + k0, lB);
        GLL16(pb + k0 + (size_t)64 * K, lB + 64 * 32);
        __syncthreads();
        bf16x8 af[MI], bfv[NI];
#pragma unroll
        for (int mi = 0; mi < MI; ++mi) af[mi] = *(const bf16x8*)&as[wr + mi * 16 + fr][fq * 8];
#pragma unroll
        for (int ni = 0; ni < NI; ++ni) bfv[ni] = *(const bf16x8*)&bs[wc + ni * 16 + fr][fq * 8];
#pragma unroll
        for (int mi = 0; mi < MI; ++mi)
#pragma unroll
            for (int ni = 0; ni < NI; ++ni)
                acc[mi][ni] = MFMA16(af[mi], bfv[ni], acc[mi][ni]);
    }

    float s = 0.f, ss = 0.f;
    const float murs = mu * rstd;
#pragma unroll
    for (int mi = 0; mi < MI; ++mi) {
#pragma unroll
        for (int ni = 0; ni < NI; ++ni) {
            const int n = n0 + wc + ni * 16 + fr;
#pragma unroll
            for (int reg = 0; reg < 4; ++reg) {
                const int r = m0 + wr + mi * 16 + fq * 4 + reg;
                float val = acc[mi][ni][reg];
                if constexpr (MODE == 0) {
                    const int p = n >> 9, hd = n & 511, d = n & 63, hh = (n >> 6) & 7;
                    const int bb = r >> 7, tt = r & 127;
                    const float* bias = (p == 0) ? b0 : (p == 1 ? b1 : b2);
                    val = val * rstd + bias[hd] - murs * cs[n];
                    const size_t bh = (size_t)(bb * 8 + hh);
                    if (p == 0)      o0[(bh * 128 + tt) * 64 + d] = (bf16)val;
                    else if (p == 1) o1[(bh * 128 + tt) * 64 + d] = (bf16)val;
                    else             o2[(bh * 64 + d) * 128 + tt] = (bf16)val;
                } else if constexpr (MODE == 1) {
                    const int d = n & 63, hh = (n >> 6) & 7;
                    const int bb = r >> 7, tt = r & 127;
                    val = val * rstd + b0[n] - murs * cs[n];
                    o0[((size_t)(bb * 8 + hh) * 128 + tt) * 64 + d] = (bf16)val;
                } else if constexpr (MODE == 2) {
                    const int p = n >> 9, hd = n & 511, d = n & 63, hh = (n >> 6) & 7;
                    const int bb = r >> 7, tt = r & 127;
                    val += (p == 0) ? b1[hd] : b2[hd];
                    const size_t bh = (size_t)(bb * 8 + hh);
                    if (p == 0) o1[(bh * 128 + tt) * 64 + d] = (bf16)val;
                    else        o2[(bh * 64 + d) * 128 + tt] = (bf16)val;
                } else if constexpr (MODE == 3) {
                    val = val * rstd + b0[n] - murs * cs[n];
                    val = fmaxf(val, 0.f);
                    o0[(size_t)r * 2048 + n] = (bf16)val;
                } else {  // MODE 4: residual-normfix add + fused stats
                    const size_t idx = (size_t)r * 512 + n;
                    const float v = (y[idx] - mu) * rstd + val + b0[n];
                    y[idx] = v;
                    ybf[idx] = (bf16)v;
                    s += v;
                    ss += v * v;
                }
            }
        }
    }
    if constexpr (MODE == 4) {
        for (int off = 32; off; off >>= 1) { s += __shfl_xor(s, off); ss += __shfl_xor(ss, off); }
        __shared__ float rs[4], rss[4];
        if (lane == 0) { rs[wave] = s; rss[wave] = ss; }
        __syncthreads();
        if (tid == 0) {
            float2* dst = &part[slotNew * 64 + (m0 >> 7)];
            atomicAdd(&dst->x, rs[0] + rs[1] + rs[2] + rs[3]);
            atomicAdd(&dst->y, rss[0] + rss[1] + rss[2] + rss[3]);
        }
    }
}

// ---------------------------------------------------------------------------
// Attention for one (b,h). Epilogue: y += normfix(residual) + softmax(QK/8)V,
// writes y fp32 + ybf bf16, fused (sum,sumsq) stats -> part[slotNew].
__global__ __launch_bounds__(256) void attn_kernel(
    const bf16* __restrict__ q, const bf16* __restrict__ k,
    const bf16* __restrict__ vT, float* __restrict__ y, bf16* __restrict__ ybf,
    float2* __restrict__ part, int slotPrev, int slotNew)
{
    __shared__ alignas(16) bf16 sP[128][136];
    __shared__ float sInv[128];
    const int bh = blockIdx.x;
    const int bb = bh >> 3, hh = bh & 7;
    const bf16* Q = q + (size_t)bh * 128 * 64;
    const bf16* Kp = k + (size_t)bh * 128 * 64;
    const bf16* V = vT + (size_t)bh * 64 * 128;
    const int tid = threadIdx.x, wave = tid >> 6, lane = tid & 63;
    const int wr = (wave >> 1) * 64, wc = (wave & 1) * 64;
    const int fr = lane & 15, fq = lane >> 4;

    float mu = 0.f, rstd = 1.f;
    if (slotPrev >= 0) {
        float2 p = part[slotPrev * 64 + bb];
        mu = p.x * LNINV;
        rstd = rsqrtf(p.y * LNINV - mu * mu + EPS_);
    }

    // S = Q K^T (128x128, K=64)
    f32x4 acc[4][4] = {};
#pragma unroll
    for (int k0 = 0; k0 < 64; k0 += 32) {
        bf16x8 af[4], bfv[4];
#pragma unroll
        for (int mi = 0; mi < 4; ++mi)
            af[mi] = *(const bf16x8*)(Q + (size_t)(wr + mi * 16 + fr) * 64 + k0 + fq * 8);
#pragma unroll
        for (int ni = 0; ni < 4; ++ni)
            bfv[ni] = *(const bf16x8*)(Kp + (size_t)(wc + ni * 16 + fr) * 64 + k0 + fq * 8);
#pragma unroll
        for (int mi = 0; mi < 4; ++mi)
#pragma unroll
            for (int ni = 0; ni < 4; ++ni)
                acc[mi][ni] = MFMA16(af[mi], bfv[ni], acc[mi][ni]);
    }
#pragma unroll
    for (int mi = 0; mi < 4; ++mi)
#pragma unroll
        for (int ni = 0; ni < 4; ++ni)
#pragma unroll
            for (int reg = 0; reg < 4; ++reg)
                sP[wr + mi * 16 + fq * 4 + reg][wc + ni * 16 + fr] =
                    (bf16)(acc[mi][ni][reg] * 0.125f);
    __syncthreads();

    // softmax rows (2 threads/row)
    {
        const int r = tid >> 1, h0 = (tid & 1) * 64;
        float mx = -3.0e38f;
        for (int j = 0; j < 64; ++j) mx = fmaxf(mx, (float)sP[r][h0 + j]);
        mx = fmaxf(mx, __shfl_xor(mx, 1));
        float sum = 0.f;
        for (int j = 0; j < 64; ++j) {
            float p = __expf((float)sP[r][h0 + j] - mx);
            sum += p;
            sP[r][h0 + j] = (bf16)p;
        }
        sum += __shfl_xor(sum, 1);
        if ((tid & 1) == 0) sInv[r] = 1.f / sum;
    }
    __syncthreads();

    // O = P V (128x64, K=128)
    f32x4 acc2[2][4] = {};
#pragma unroll
    for (int k0 = 0; k0 < 128; k0 += 32) {
        bf16x8 af[2], bfv[4];
#pragma unroll
        for (int mi = 0; mi < 2; ++mi)
            af[mi] = *(const bf16x8*)&sP[wave * 32 + mi * 16 + fr][k0 + fq * 8];
#pragma unroll
        for (int ni = 0; ni < 4; ++ni)
            bfv[ni] = *(const bf16x8*)(V + (size_t)(ni * 16 + fr) * 128 + k0 + fq * 8);
#pragma unroll
        for (int mi = 0; mi < 2; ++mi)
#pragma unroll
            for (int ni = 0; ni < 4; ++ni)
                acc2[mi][ni] = MFMA16(af[mi], bfv[ni], acc2[mi][ni]);
    }

    float s = 0.f, ss = 0.f;
#pragma unroll
    for (int mi = 0; mi < 2; ++mi)
#pragma unroll
        for (int ni = 0; ni < 4; ++ni)
#pragma unroll
            for (int reg = 0; reg < 4; ++reg) {
                const int r = wave * 32 + mi * 16 + fq * 4 + reg;
                const int d = ni * 16 + fr;
                const size_t idx = ((size_t)(bb * 128 + r)) * 512 + hh * 64 + d;
                const float v = (y[idx] - mu) * rstd + acc2[mi][ni][reg] * sInv[r];
                y[idx] = v;
                ybf[idx] = (bf16)v;
                s += v;
                ss += v * v;
            }
    for (int off = 32; off; off >>= 1) { s += __shfl_xor(s, off); ss += __shfl_xor(ss, off); }
    __shared__ float rs[4], rss[4];
    if (lane == 0) { rs[wave] = s; rss[wave] = ss; }
    __syncthreads();
    if (tid == 0) {
        float2* dst = &part[slotNew * 64 + bb];
        atomicAdd(&dst->x, rs[0] + rs[1] + rs[2] + rs[3]);
        atomicAdd(&dst->y, rss[0] + rss[1] + rss[2] + rss[3]);
    }
}

// ---------------------------------------------------------------------------
// d_out = (y - mu) * rstd, fp32. grid 4096 x 256, 4 elems/thread.
__global__ __launch_bounds__(256) void final_norm(
    const float* __restrict__ y, const float2* __restrict__ part, int slot,
    float* __restrict__ out)
{
    const size_t i = ((size_t)blockIdx.x * 256 + threadIdx.x) * 4;
    const int b = (int)(i >> 16);
    float2 p = part[slot * 64 + b];
    const float mu = p.x * LNINV;
    const float rstd = rsqrtf(p.y * LNINV - mu * mu + EPS_);
    float4 v = *(const float4*)(y + i);
    float4 o = {(v.x - mu) * rstd, (v.y - mu) * rstd, (v.z - mu) * rstd, (v.w - mu) * rstd};
    *(float4*)(out + i) = o;
}

// ---------------------------------------------------------------------------
extern "C" void kernel_launch(void* const* d_in, const int* in_sizes, int n_in,
                              void* d_out, int out_size, void* d_ws, size_t ws_size,
                              hipStream_t stream)
{
    (void)in_sizes; (void)n_in; (void)out_size; (void)ws_size;
    const float* x_in  = (const float*)d_in[0];
    const float* enc   = (const float*)d_in[1];
    const float* sa_wq = (const float*)d_in[2];
    const float* sa_bq = (const float*)d_in[3];
    const float* sa_wk = (const float*)d_in[4];
    const float* sa_bk = (const float*)d_in[5];
    const float* sa_wv = (const float*)d_in[6];
    const float* sa_bv = (const float*)d_in[7];
    const float* ca_wq = (const float*)d_in[8];
    const float* ca_bq = (const float*)d_in[9];
    const float* ca_wk = (const float*)d_in[10];
    const float* ca_bk = (const float*)d_in[11];
    const float* ca_wv = (const float*)d_in[12];
    const float* ca_bv = (const float*)d_in[13];
    const float* ff_w1 = (const float*)d_in[14];
    const float* ff_b1 = (const float*)d_in[15];
    const float* ff_w2 = (const float*)d_in[16];
    const float* ff_b2 = (const float*)d_in[17];

    char* wsp = (char*)d_ws;
    auto alloc = [&](size_t bytes) -> char* {
        char* p = wsp;
        wsp += (bytes + 255) & ~(size_t)255;
        return p;
    };
    float* y     = (float*)alloc((size_t)M_ * 512 * 4);           // unnormalized stream
    bf16*  ybf   = (bf16*)alloc((size_t)M_ * 512 * 2);            // bf16 GEMM operand
    bf16*  encbf = (bf16*)alloc((size_t)M_ * 512 * 2);
    char*  shreg = alloc((size_t)M_ * 2048 * 2);                  // qkv bufs / FFN hidden
    bf16*  WsaA  = (bf16*)alloc((size_t)L_ * 1536 * 512 * 2);     // repacked, all layers
    bf16*  WcaqA = (bf16*)alloc((size_t)L_ * 512 * 512 * 2);
    bf16*  WcakvA= (bf16*)alloc((size_t)L_ * 1024 * 512 * 2);
    bf16*  Wff1  = (bf16*)alloc((size_t)2048 * 512 * 2);          // per-layer
    bf16*  Wff2  = (bf16*)alloc((size_t)512 * 2048 * 2);
    float* csA   = (float*)alloc((size_t)L_ * 1536 * 4);          // colsums
    float* csQ   = (float*)alloc((size_t)L_ * 512 * 4);
    float* csF   = (float*)alloc((size_t)L_ * 2048 * 4);
    float2* part = (float2*)alloc(18 * 64 * sizeof(float2));

    bf16* qb   = (bf16*)shreg;
    bf16* kb   = (bf16*)(shreg + (size_t)512 * 128 * 64 * 2);
    bf16* vTb  = (bf16*)(shreg + (size_t)2 * 512 * 128 * 64 * 2);
    bf16* hbuf = (bf16*)shreg;  // overlaps qkv (disjoint lifetime)

    dim3 tb(256);
    zero_part<<<1, tb, 0, stream>>>((float*)part);
    init_x<<<2048, tb, 0, stream>>>(x_in, y, ybf);
    to_bf16<<<2048, tb, 0, stream>>>(enc, encbf);
    head_repack<<<dim3(1, 8, 288), tb, 0, stream>>>(sa_wq, sa_wk, sa_wv, ca_wq, ca_wk, ca_wv,
                                                    WsaA, WcaqA, WcakvA);
    colsum_all<<<96, tb, 0, stream>>>(sa_wq, sa_wk, sa_wv, ca_wq, ff_w1, csA, csQ, csF);

    for (int l = 0; l < L_; ++l) {
        transpose_f32_bf16<<<dim3(32, 8, 1), tb, 0, stream>>>(ff_w1 + (size_t)l * 512 * 2048, Wff1, 512, 2048);
        transpose_f32_bf16<<<dim3(8, 32, 1), tb, 0, stream>>>(ff_w2 + (size_t)l * 2048 * 512, Wff2, 2048, 512);
        const int sPrev = (l == 0) ? -1 : (l - 1) * 3 + 2;
        // ---- self attention
        gemm_bt<0, 128><<<dim3(12, 64), tb, 0, stream>>>(ybf, WsaA + (size_t)l * 1536 * 512,
            sa_bq + l * 512, sa_bk + l * 512, sa_bv + l * 512, csA + l * 1536,
            part, sPrev, -1, qb, kb, vTb, nullptr, nullptr, 1536, 512);
        attn_kernel<<<512, tb, 0, stream>>>(qb, kb, vTb, y, ybf, part, sPrev, l * 3 + 0);
        // ---- cross attention
        gemm_bt<1, 64><<<dim3(4, 128), tb, 0, stream>>>(ybf, WcaqA + (size_t)l * 512 * 512,
            ca_bq + l * 512, nullptr, nullptr, csQ + l * 512,
            part, l * 3 + 0, -1, qb, nullptr, nullptr, nullptr, nullptr, 512, 512);
        gemm_bt<2, 128><<<dim3(8, 64), tb, 0, stream>>>(encbf, WcakvA + (size_t)l * 1024 * 512,
            nullptr, ca_bk + l * 512, ca_bv + l * 512, nullptr,
            part, -1, -1, nullptr, kb, vTb, nullptr, nullptr, 1024, 512);
        attn_kernel<<<512, tb, 0, stream>>>(qb, kb, vTb, y, ybf, part, l * 3 + 0, l * 3 + 1);
        // ---- feed-forward
        gemm_bt<3, 128><<<dim3(16, 64), tb, 0, stream>>>(ybf, Wff1,
            ff_b1 + l * 2048, nullptr, nullptr, csF + l * 2048,
            part, l * 3 + 1, -1, hbuf, nullptr, nullptr, nullptr, nullptr, 2048, 512);
        gemm_bt<4, 64><<<dim3(4, 128), tb, 0, stream>>>(hbuf, Wff2,
            ff_b2 + l * 512, nullptr, nullptr, nullptr,
            part, l * 3 + 1, l * 3 + 2, nullptr, nullptr, nullptr, y, ybf, 512, 2048);
    }
    final_norm<<<4096, tb, 0, stream>>>(y, part, 17, (float*)d_out);
}